// Round 6
// baseline (137.614 us; speedup 1.0000x reference)
//
#include <hip/hip_runtime.h>
#include <hip/hip_bf16.h>

typedef _Float16 f16x8 __attribute__((ext_vector_type(8)));
typedef _Float16 f16x4 __attribute__((ext_vector_type(4)));
typedef __fp16 fp16x2 __attribute__((ext_vector_type(2)));
typedef float f32x4 __attribute__((ext_vector_type(4)));

#define BATCH 4
#define SEQ 4096
#define EMB 1024
#define HEAD 64

// Async global->LDS, 16B per lane. LDS dest is WAVE-UNIFORM base; HW adds
// lane*16. Global src is per-lane (we make it base + lane*16 = coalesced,
// or pre-swizzled for conflict-free LDS reads — m173 pattern).
__device__ __forceinline__ void async_copy16(const void* gsrc, void* ldst) {
  __builtin_amdgcn_global_load_lds(
      (const __attribute__((address_space(1))) void*)gsrc,
      (__attribute__((address_space(3))) void*)ldst,
      16, 0, 0);
}

// ---------------------------------------------------------------------------
// Kernel 1: weights -> glds-tiled WT (unchanged).
// ---------------------------------------------------------------------------
__global__ __launch_bounds__(256) void wtrans_kernel(
    const float* __restrict__ Wk, const float* __restrict__ Wq,
    const float* __restrict__ Wv, _Float16* __restrict__ WT) {
  int id = blockIdx.x * 256 + threadIdx.x;   // 0 .. 24575 (unit index)
  int step = id / 1536;
  int rem = id - step * 1536;
  int G = rem / 192;
  int n = rem - G * 192;
  int sel = n >> 6;
  int col = n & 63;
  const float* src = (sel == 0) ? Wq : (sel == 1) ? Wk : Wv;
  const float scale = (sel == 0) ? 0.03125f : 1.0f;
  f16x8 u;
#pragma unroll
  for (int j = 0; j < 8; ++j) {
    int k = step * 64 + G * 8 + j;
    u[j] = (_Float16)(src[k * 64 + col] * scale);
  }
  *(f16x8*)(WT + (size_t)id * 8) = u;
}

// ---------------------------------------------------------------------------
// Kernel 2: QKV projection — counted-vmcnt pipeline (T3/T4, m201 pattern).
// M=32 tile, grid 512 (2 blocks/CU), 4 waves 2x2, BK=64, 16 steps.
// __syncthreads' implicit vmcnt(0) drained the whole glds queue every step,
// exposing full staging latency (R4/R5: MfmaUtil 5%, latency-bound). Now:
//   raw s_barrier + counted s_waitcnt vmcnt(2); NEVER drain in the loop.
//   WT: double-buffer, issued 1 step ahead (6 chunks/wave, L2/L3 path).
//   x:  ring of 3, issued 2 steps ahead (2 chunks/wave, HBM path ~900cy
//       covered by 2 steps of compute). Swizzled src/read as before.
// Per step: wait vmcnt(2) [retires WT(s)+x(s), leaves x(s+1)] -> s_barrier
// -> issue WT(s+1), x(s+2) -> compute. FIFO: outstanding 10 -> 2.
// WAR-safe under raw barrier: every ds_read is consumed (lgkm-waited)
// before the wave reaches the barrier. LDS 48+24=72KB -> 2 blocks/CU.
// ---------------------------------------------------------------------------
__global__ __launch_bounds__(256) void proj_kernel(
    const float* __restrict__ x, const _Float16* __restrict__ WT,
    _Float16* __restrict__ Qh, _Float16* __restrict__ KT,
    _Float16* __restrict__ VT) {
  __shared__ _Float16 wtl[2][12288];   // 2 x 24 KB, unit u = G*192 + n
  __shared__ float xls[3][32 * 64];    // 3 x 8 KB x tile ring, swizzled units
  const int tid = threadIdx.x;
  const int wave = tid >> 6;
  const int lane = tid & 63;
  const int quad = lane >> 4;
  const int l16 = lane & 15;
  const int wm = wave & 1;
  const int wn = wave >> 1;
  const int rowblk = blockIdx.x * 32;

  // x staging geometry: chunk c covers tile rows 4c..4c+3; lane -> row
  // 4c + (lane>>4), LDS unit position pos = lane&15; global unit
  // u = pos ^ (row&7) (involution; read applies the same XOR).
  const int lq = lane >> 4;
  const int pos = lane & 15;

  f32x4 acc[6];
#pragma unroll
  for (int t = 0; t < 6; ++t) acc[t] = (f32x4){0.f, 0.f, 0.f, 0.f};

  // prologue: WT(0) -> wtl[0]; x(0) -> xls[0]; x(1) -> xls[1]
#pragma unroll
  for (int i = 0; i < 6; ++i) {
    const int c = wave * 6 + i;
    async_copy16(WT + (size_t)c * 512 + lane * 8, (char*)&wtl[0][0] + c * 1024);
  }
#pragma unroll
  for (int i = 0; i < 2; ++i) {
    const int c = wave * 2 + i;
    const int rts = c * 4 + lq;
    const int u = pos ^ (rts & 7);
    async_copy16(x + (size_t)(rowblk + rts) * EMB + u * 4,
                 (char*)&xls[0][0] + c * 1024);
  }
#pragma unroll
  for (int i = 0; i < 2; ++i) {
    const int c = wave * 2 + i;
    const int rts = c * 4 + lq;
    const int u = pos ^ (rts & 7);
    async_copy16(x + (size_t)(rowblk + rts) * EMB + 64 + u * 4,
                 (char*)&xls[1][0] + c * 1024);
  }

  // read-side swizzled x offsets (tile-local row rt, 16B units)
  const int rt = wm * 16 + l16;
  const int rb = rt & 7;
  const int ua = ((quad * 2) ^ rb) * 4;        // floats [quad*8,   +4)
  const int ub = ((quad * 2 + 1) ^ rb) * 4;    // floats [quad*8+4, +4)
  const int uc = ((8 + quad * 2) ^ rb) * 4;    // floats [quad*8+32, +4)
  const int ud = ((8 + quad * 2 + 1) ^ rb) * 4;

  int pw = 0;        // wtl parity for current step
  int x3 = 0;        // xls ring slot for current step
  int x3i = 2;       // xls ring slot for step+2
  for (int step = 0; step < 16; ++step) {
    // counted wait: retire WT(step)+x(step); keep x(step+1) in flight.
    if (step < 15) {
      asm volatile("s_waitcnt vmcnt(2)" ::: "memory");
    } else {
      asm volatile("s_waitcnt vmcnt(0)" ::: "memory");
    }
    __builtin_amdgcn_sched_barrier(0);
    __builtin_amdgcn_s_barrier();      // publish staged LDS to all waves

    // issue next stages (never waited this step)
    if (step + 1 < 16) {
      const _Float16* wsrc = WT + (size_t)(step + 1) * 12288;
#pragma unroll
      for (int i = 0; i < 6; ++i) {
        const int c = wave * 6 + i;
        async_copy16(wsrc + (size_t)c * 512 + lane * 8,
                     (char*)&wtl[pw ^ 1][0] + c * 1024);
      }
    }
    if (step + 2 < 16) {
      const float* xsrc = x + (size_t)(step + 2) * 64;
#pragma unroll
      for (int i = 0; i < 2; ++i) {
        const int c = wave * 2 + i;
        const int rts = c * 4 + lq;
        const int u = pos ^ (rts & 7);
        async_copy16(xsrc + (size_t)(rowblk + rts) * EMB + u * 4,
                     (char*)&xls[x3i][0] + c * 1024);
      }
    }

    // x frags from LDS (swizzled float4 reads, ~2-way = free)
    const float* xl = &xls[x3][rt * 64];
    const float4 xa = *(const float4*)(xl + ua);
    const float4 xb = *(const float4*)(xl + ub);
    const float4 xc = *(const float4*)(xl + uc);
    const float4 xd = *(const float4*)(xl + ud);
    fp16x2 p0 = __builtin_amdgcn_cvt_pkrtz(xa.x, xa.y);
    fp16x2 p1 = __builtin_amdgcn_cvt_pkrtz(xa.z, xa.w);
    fp16x2 p2 = __builtin_amdgcn_cvt_pkrtz(xb.x, xb.y);
    fp16x2 p3 = __builtin_amdgcn_cvt_pkrtz(xb.z, xb.w);
    f16x8 af0, af1;
    af0[0] = (_Float16)p0[0]; af0[1] = (_Float16)p0[1];
    af0[2] = (_Float16)p1[0]; af0[3] = (_Float16)p1[1];
    af0[4] = (_Float16)p2[0]; af0[5] = (_Float16)p2[1];
    af0[6] = (_Float16)p3[0]; af0[7] = (_Float16)p3[1];
    p0 = __builtin_amdgcn_cvt_pkrtz(xc.x, xc.y);
    p1 = __builtin_amdgcn_cvt_pkrtz(xc.z, xc.w);
    p2 = __builtin_amdgcn_cvt_pkrtz(xd.x, xd.y);
    p3 = __builtin_amdgcn_cvt_pkrtz(xd.z, xd.w);
    af1[0] = (_Float16)p0[0]; af1[1] = (_Float16)p0[1];
    af1[2] = (_Float16)p1[0]; af1[3] = (_Float16)p1[1];
    af1[4] = (_Float16)p2[0]; af1[5] = (_Float16)p2[1];
    af1[6] = (_Float16)p3[0]; af1[7] = (_Float16)p3[1];
    // compute: 12 B-frag LDS reads + 12 MFMA
#pragma unroll
    for (int t = 0; t < 6; ++t) {
      const int n = wn * 96 + t * 16 + l16;
      const f16x8 b0 = *(const f16x8*)&wtl[pw][(size_t)((0 * 4 + quad) * 192 + n) * 8];
      const f16x8 b1 = *(const f16x8*)&wtl[pw][(size_t)((1 * 4 + quad) * 192 + n) * 8];
      acc[t] = __builtin_amdgcn_mfma_f32_16x16x32_f16(af0, b0, acc[t], 0, 0, 0);
      acc[t] = __builtin_amdgcn_mfma_f32_16x16x32_f16(af1, b1, acc[t], 0, 0, 0);
    }
    pw ^= 1;
    x3 = (x3 == 2) ? 0 : x3 + 1;
    x3i = (x3i == 2) ? 0 : x3i + 1;
  }

  // Epilogue. C-layout: row = rowbase + quad*4 + r, col(l16) within tile.
  const int rowbase = rowblk + wm * 16;
  const int b = rowbase >> 12;
  const int trbase = (rowbase & 4095) + quad * 4;
#pragma unroll
  for (int t = 0; t < 6; ++t) {
    const int g = wn * 6 + t;
    if (g < 4) {                         // Q row-major (scaled via Wq)
      const int h = g * 16 + l16;
#pragma unroll
      for (int r = 0; r < 4; ++r)
        Qh[(size_t)(rowbase + quad * 4 + r) * HEAD + h] = (_Float16)acc[t][r];
    } else if (g < 8) {                  // K -> KT[b][kt][G=h/8][key][h%8]
      const int h = (g - 4) * 16 + l16;
#pragma unroll
      for (int r = 0; r < 4; ++r) {
        const int t0 = trbase + r;
        const size_t ad = ((size_t)((b * 64 + (t0 >> 6)) * 8 + (h >> 3)) * 64 +
                           (t0 & 63)) * 8 + (h & 7);
        KT[ad] = (_Float16)acc[t][r];
      }
    } else {                             // V -> VT[b][kt][Gk=keygrp][h][key%8]
      const int h = (g - 8) * 16 + l16;
      f16x4 pk;
      pk[0] = (_Float16)acc[t][0]; pk[1] = (_Float16)acc[t][1];
      pk[2] = (_Float16)acc[t][2]; pk[3] = (_Float16)acc[t][3];
      const size_t ad = ((size_t)((b * 64 + (trbase >> 6)) * 8 + ((trbase & 63) >> 3)) * 512) +
                        (size_t)h * 8 + (trbase & 7);
      *(f16x4*)(VT + ad) = pk;
    }
  }
}

// ---------------------------------------------------------------------------
// Kernel 3: causal flash attention — wave-private, barrier-free main loop
// (unchanged from R4: ~17 us by dispatch-budget reconciliation).
// ---------------------------------------------------------------------------
__global__ __launch_bounds__(256) void flash_kernel(
    const _Float16* __restrict__ Qh, const _Float16* __restrict__ KT,
    const _Float16* __restrict__ VT, float* __restrict__ out) {
  __shared__ _Float16 myp[4][16 * 68];  // wave-private P, stride 68 halves
  __shared__ float lds_o[2][16][68];    // per-tile O partial (odd wave)
  __shared__ float lds_l[2][16];        // per-tile l partial (odd wave)
  const int tid = threadIdx.x;
  const int w = tid >> 6;
  const int lane = tid & 63;
  const int quad = lane >> 4;
  const int l16 = lane & 15;
  const int b = blockIdx.x & 3;
  const int jj = blockIdx.x >> 2;       // 0..127
  const int t = w >> 1;                 // local tile slot (0,1)
  const int kh = w & 1;                 // kt-range half
  const int j = t ? (255 - jj) : jj;    // tile index within batch
  const int qb = j * 16;
  const int nkt = (j >> 2) + 1;
  const int h1 = (nkt + 1) >> 1;        // split point
  const int lo = kh ? h1 : 0;
  const int hi = kh ? nkt : h1;

  const _Float16* Q = Qh + (size_t)b * SEQ * HEAD;
  const _Float16* KTb = KT + (size_t)b * 64 * 4096;  // 4096 halves per kt
  const _Float16* VTb = VT + (size_t)b * 64 * 4096;
  const f32x4 zero = {0.f, 0.f, 0.f, 0.f};
  _Float16* mp = &myp[w][0];

  // Q A-frags, loaded once
  const f16x8 aq0 = *(const f16x8*)(Q + (size_t)(qb + l16) * HEAD + quad * 8);
  const f16x8 aq1 = *(const f16x8*)(Q + (size_t)(qb + l16) * HEAD + 32 + quad * 8);
  const int qrow = qb + quad * 4;       // +r

  f32x4 oc[4];
#pragma unroll
  for (int m = 0; m < 4; ++m) oc[m] = zero;
  float lacc[4] = {0.f, 0.f, 0.f, 0.f};

  // K frags for first kt (loop-carried prefetch)
  f16x8 ka[4], kb[4];
  if (lo < hi) {
    const _Float16* kp = KTb + (size_t)lo * 4096;
#pragma unroll
    for (int s = 0; s < 4; ++s) {
      ka[s] = *(const f16x8*)(kp + (size_t)quad * 512 + (s * 16 + l16) * 8);
      kb[s] = *(const f16x8*)(kp + (size_t)(4 + quad) * 512 + (s * 16 + l16) * 8);
    }
  }

  for (int kt = lo; kt < hi; ++kt) {
    // V frag loads (consumed after QK+exp — latency self-hiding)
    const _Float16* vp = VTb + (size_t)kt * 4096;
    f16x8 va[4], vb[4];
#pragma unroll
    for (int m = 0; m < 4; ++m) {
      va[m] = *(const f16x8*)(vp + (size_t)quad * 512 + (m * 16 + l16) * 8);
      vb[m] = *(const f16x8*)(vp + (size_t)(4 + quad) * 512 + (m * 16 + l16) * 8);
    }

    // QK: full 64 keys, 4 key-subtiles x (2 MFMA over h=64)
    f32x4 sc[4];
#pragma unroll
    for (int s = 0; s < 4; ++s) {
      sc[s] = __builtin_amdgcn_mfma_f32_16x16x32_f16(aq0, ka[s], zero, 0, 0, 0);
      sc[s] = __builtin_amdgcn_mfma_f32_16x16x32_f16(aq1, kb[s], sc[s], 0, 0, 0);
    }

    // prefetch next step's K (loop-carried, overlaps exp/P/PV)
    if (kt + 1 < hi) {
      const _Float16* kp = KTb + (size_t)(kt + 1) * 4096;
#pragma unroll
      for (int s = 0; s < 4; ++s) {
        ka[s] = *(const f16x8*)(kp + (size_t)quad * 512 + (s * 16 + l16) * 8);
        kb[s] = *(const f16x8*)(kp + (size_t)(4 + quad) * 512 + (s * 16 + l16) * 8);
      }
    }

    // mask (diagonal step only) + exp + wave-private P write
    const int kbase = kt * 64;
    if (kt == nkt - 1) {
#pragma unroll
      for (int s = 0; s < 4; ++s) {
#pragma unroll
        for (int r = 0; r < 4; ++r) {
          const float pv = (kbase + s * 16 + l16 > qrow + r) ? 0.f : __expf(sc[s][r]);
          lacc[r] += pv;
          mp[(quad * 4 + r) * 68 + s * 16 + l16] = (_Float16)pv;
        }
      }
    } else {
#pragma unroll
      for (int s = 0; s < 4; ++s) {
#pragma unroll
        for (int r = 0; r < 4; ++r) {
          const float pv = __expf(sc[s][r]);
          lacc[r] += pv;
          mp[(quad * 4 + r) * 68 + s * 16 + l16] = (_Float16)pv;
        }
      }
    }

    // P A-frags (wave-private round trip, lgkmcnt-ordered, no barrier)
    const f16x8 ap0 = *(const f16x8*)(mp + l16 * 68 + quad * 8);
    const f16x8 ap1 = *(const f16x8*)(mp + l16 * 68 + 32 + quad * 8);

    // PV: 4 h-subtiles x (2 MFMA over k=64)
#pragma unroll
    for (int m = 0; m < 4; ++m) {
      oc[m] = __builtin_amdgcn_mfma_f32_16x16x32_f16(ap0, va[m], oc[m], 0, 0, 0);
      oc[m] = __builtin_amdgcn_mfma_f32_16x16x32_f16(ap1, vb[m], oc[m], 0, 0, 0);
    }
  }

  // reduce row sums over the lane's 16-key slice partners (l16 bits)
  float lr[4];
#pragma unroll
  for (int r = 0; r < 4; ++r) {
    float l = lacc[r];
    l += __shfl_xor(l, 1);
    l += __shfl_xor(l, 2);
    l += __shfl_xor(l, 4);
    l += __shfl_xor(l, 8);
    lr[r] = l;
  }

  // odd wave deposits partials; even wave combines + writes
  if (kh) {
#pragma unroll
    for (int r = 0; r < 4; ++r) {
      if (l16 == 0) lds_l[t][quad * 4 + r] = lr[r];
#pragma unroll
      for (int m = 0; m < 4; ++m)
        lds_o[t][quad * 4 + r][m * 16 + l16] = oc[m][r];
    }
  }
  __syncthreads();
  if (!kh) {
#pragma unroll
    for (int r = 0; r < 4; ++r) {
      const float lsum = lr[r] + lds_l[t][quad * 4 + r];
      const float inv = 1.0f / lsum;
      float* op = out + ((size_t)b * SEQ + qb + quad * 4 + r) * HEAD + l16;
#pragma unroll
      for (int m = 0; m < 4; ++m)
        op[m * 16] = (oc[m][r] + lds_o[t][quad * 4 + r][m * 16 + l16]) * inv;
    }
  }
}

extern "C" void kernel_launch(void* const* d_in, const int* in_sizes, int n_in,
                              void* d_out, int out_size, void* d_ws, size_t ws_size,
                              hipStream_t stream) {
  const float* x  = (const float*)d_in[0];
  const float* Wk = (const float*)d_in[1];
  const float* Wq = (const float*)d_in[2];
  const float* Wv = (const float*)d_in[3];
  float* out = (float*)d_out;

  // ws layout: Qh[0,2MB) KT[2MB,4MB) VT[4MB,6MB) WT[6MB,6.375MB)
  char* ws = (char*)d_ws;
  _Float16* Qh = (_Float16*)(ws);
  _Float16* KT = (_Float16*)(ws + (size_t)2 * 1024 * 1024);
  _Float16* VT = (_Float16*)(ws + (size_t)4 * 1024 * 1024);
  _Float16* WT = (_Float16*)(ws + (size_t)6 * 1024 * 1024);

  wtrans_kernel<<<96, 256, 0, stream>>>(Wk, Wq, Wv, WT);
  proj_kernel<<<512, 256, 0, stream>>>(x, WT, Qh, KT, VT);
  flash_kernel<<<512, 256, 0, stream>>>(Qh, KT, VT, out);
}

// Round 7
// 135.738 us; speedup vs baseline: 1.0138x; 1.0138x over previous
//
#include <hip/hip_runtime.h>
#include <hip/hip_bf16.h>

typedef _Float16 f16x8 __attribute__((ext_vector_type(8)));
typedef _Float16 f16x4 __attribute__((ext_vector_type(4)));
typedef __fp16 fp16x2 __attribute__((ext_vector_type(2)));
typedef float f32x4 __attribute__((ext_vector_type(4)));

#define BATCH 4
#define SEQ 4096
#define EMB 1024
#define HEAD 64

// Async global->LDS, 16B per lane. LDS dest is WAVE-UNIFORM base; HW adds
// lane*16. Global src is per-lane (we make it base + lane*16 = coalesced,
// or pre-swizzled for conflict-free LDS reads — m173 pattern).
__device__ __forceinline__ void async_copy16(const void* gsrc, void* ldst) {
  __builtin_amdgcn_global_load_lds(
      (const __attribute__((address_space(1))) void*)gsrc,
      (__attribute__((address_space(3))) void*)ldst,
      16, 0, 0);
}

// ---------------------------------------------------------------------------
// Kernel 1: weights -> glds-tiled WT (unchanged).
// ---------------------------------------------------------------------------
__global__ __launch_bounds__(256) void wtrans_kernel(
    const float* __restrict__ Wk, const float* __restrict__ Wq,
    const float* __restrict__ Wv, _Float16* __restrict__ WT) {
  int id = blockIdx.x * 256 + threadIdx.x;   // 0 .. 24575 (unit index)
  int step = id / 1536;
  int rem = id - step * 1536;
  int G = rem / 192;
  int n = rem - G * 192;
  int sel = n >> 6;
  int col = n & 63;
  const float* src = (sel == 0) ? Wq : (sel == 1) ? Wk : Wv;
  const float scale = (sel == 0) ? 0.03125f : 1.0f;
  f16x8 u;
#pragma unroll
  for (int j = 0; j < 8; ++j) {
    int k = step * 64 + G * 8 + j;
    u[j] = (_Float16)(src[k * 64 + col] * scale);
  }
  *(f16x8*)(WT + (size_t)id * 8) = u;
}

// ---------------------------------------------------------------------------
// Kernel 2: QKV projection — counted-vmcnt pipeline (unchanged from R6).
// ---------------------------------------------------------------------------
__global__ __launch_bounds__(256) void proj_kernel(
    const float* __restrict__ x, const _Float16* __restrict__ WT,
    _Float16* __restrict__ Qh, _Float16* __restrict__ KT,
    _Float16* __restrict__ VT) {
  __shared__ _Float16 wtl[2][12288];   // 2 x 24 KB, unit u = G*192 + n
  __shared__ float xls[3][32 * 64];    // 3 x 8 KB x tile ring, swizzled units
  const int tid = threadIdx.x;
  const int wave = tid >> 6;
  const int lane = tid & 63;
  const int quad = lane >> 4;
  const int l16 = lane & 15;
  const int wm = wave & 1;
  const int wn = wave >> 1;
  const int rowblk = blockIdx.x * 32;

  const int lq = lane >> 4;
  const int pos = lane & 15;

  f32x4 acc[6];
#pragma unroll
  for (int t = 0; t < 6; ++t) acc[t] = (f32x4){0.f, 0.f, 0.f, 0.f};

  // prologue: WT(0) -> wtl[0]; x(0) -> xls[0]; x(1) -> xls[1]
#pragma unroll
  for (int i = 0; i < 6; ++i) {
    const int c = wave * 6 + i;
    async_copy16(WT + (size_t)c * 512 + lane * 8, (char*)&wtl[0][0] + c * 1024);
  }
#pragma unroll
  for (int i = 0; i < 2; ++i) {
    const int c = wave * 2 + i;
    const int rts = c * 4 + lq;
    const int u = pos ^ (rts & 7);
    async_copy16(x + (size_t)(rowblk + rts) * EMB + u * 4,
                 (char*)&xls[0][0] + c * 1024);
  }
#pragma unroll
  for (int i = 0; i < 2; ++i) {
    const int c = wave * 2 + i;
    const int rts = c * 4 + lq;
    const int u = pos ^ (rts & 7);
    async_copy16(x + (size_t)(rowblk + rts) * EMB + 64 + u * 4,
                 (char*)&xls[1][0] + c * 1024);
  }

  const int rt = wm * 16 + l16;
  const int rb = rt & 7;
  const int ua = ((quad * 2) ^ rb) * 4;
  const int ub = ((quad * 2 + 1) ^ rb) * 4;
  const int uc = ((8 + quad * 2) ^ rb) * 4;
  const int ud = ((8 + quad * 2 + 1) ^ rb) * 4;

  int pw = 0;
  int x3 = 0;
  int x3i = 2;
  for (int step = 0; step < 16; ++step) {
    if (step < 15) {
      asm volatile("s_waitcnt vmcnt(2)" ::: "memory");
    } else {
      asm volatile("s_waitcnt vmcnt(0)" ::: "memory");
    }
    __builtin_amdgcn_sched_barrier(0);
    __builtin_amdgcn_s_barrier();

    if (step + 1 < 16) {
      const _Float16* wsrc = WT + (size_t)(step + 1) * 12288;
#pragma unroll
      for (int i = 0; i < 6; ++i) {
        const int c = wave * 6 + i;
        async_copy16(wsrc + (size_t)c * 512 + lane * 8,
                     (char*)&wtl[pw ^ 1][0] + c * 1024);
      }
    }
    if (step + 2 < 16) {
      const float* xsrc = x + (size_t)(step + 2) * 64;
#pragma unroll
      for (int i = 0; i < 2; ++i) {
        const int c = wave * 2 + i;
        const int rts = c * 4 + lq;
        const int u = pos ^ (rts & 7);
        async_copy16(xsrc + (size_t)(rowblk + rts) * EMB + u * 4,
                     (char*)&xls[x3i][0] + c * 1024);
      }
    }

    const float* xl = &xls[x3][rt * 64];
    const float4 xa = *(const float4*)(xl + ua);
    const float4 xb = *(const float4*)(xl + ub);
    const float4 xc = *(const float4*)(xl + uc);
    const float4 xd = *(const float4*)(xl + ud);
    fp16x2 p0 = __builtin_amdgcn_cvt_pkrtz(xa.x, xa.y);
    fp16x2 p1 = __builtin_amdgcn_cvt_pkrtz(xa.z, xa.w);
    fp16x2 p2 = __builtin_amdgcn_cvt_pkrtz(xb.x, xb.y);
    fp16x2 p3 = __builtin_amdgcn_cvt_pkrtz(xb.z, xb.w);
    f16x8 af0, af1;
    af0[0] = (_Float16)p0[0]; af0[1] = (_Float16)p0[1];
    af0[2] = (_Float16)p1[0]; af0[3] = (_Float16)p1[1];
    af0[4] = (_Float16)p2[0]; af0[5] = (_Float16)p2[1];
    af0[6] = (_Float16)p3[0]; af0[7] = (_Float16)p3[1];
    p0 = __builtin_amdgcn_cvt_pkrtz(xc.x, xc.y);
    p1 = __builtin_amdgcn_cvt_pkrtz(xc.z, xc.w);
    p2 = __builtin_amdgcn_cvt_pkrtz(xd.x, xd.y);
    p3 = __builtin_amdgcn_cvt_pkrtz(xd.z, xd.w);
    af1[0] = (_Float16)p0[0]; af1[1] = (_Float16)p0[1];
    af1[2] = (_Float16)p1[0]; af1[3] = (_Float16)p1[1];
    af1[4] = (_Float16)p2[0]; af1[5] = (_Float16)p2[1];
    af1[6] = (_Float16)p3[0]; af1[7] = (_Float16)p3[1];
#pragma unroll
    for (int t = 0; t < 6; ++t) {
      const int n = wn * 96 + t * 16 + l16;
      const f16x8 b0 = *(const f16x8*)&wtl[pw][(size_t)((0 * 4 + quad) * 192 + n) * 8];
      const f16x8 b1 = *(const f16x8*)&wtl[pw][(size_t)((1 * 4 + quad) * 192 + n) * 8];
      acc[t] = __builtin_amdgcn_mfma_f32_16x16x32_f16(af0, b0, acc[t], 0, 0, 0);
      acc[t] = __builtin_amdgcn_mfma_f32_16x16x32_f16(af1, b1, acc[t], 0, 0, 0);
    }
    pw ^= 1;
    x3 = (x3 == 2) ? 0 : x3 + 1;
    x3i = (x3i == 2) ? 0 : x3i + 1;
  }

  const int rowbase = rowblk + wm * 16;
  const int b = rowbase >> 12;
  const int trbase = (rowbase & 4095) + quad * 4;
#pragma unroll
  for (int t = 0; t < 6; ++t) {
    const int g = wn * 6 + t;
    if (g < 4) {                         // Q row-major (scaled via Wq)
      const int h = g * 16 + l16;
#pragma unroll
      for (int r = 0; r < 4; ++r)
        Qh[(size_t)(rowbase + quad * 4 + r) * HEAD + h] = (_Float16)acc[t][r];
    } else if (g < 8) {                  // K -> KT[b][kt][G=h/8][key][h%8]
      const int h = (g - 4) * 16 + l16;
#pragma unroll
      for (int r = 0; r < 4; ++r) {
        const int t0 = trbase + r;
        const size_t ad = ((size_t)((b * 64 + (t0 >> 6)) * 8 + (h >> 3)) * 64 +
                           (t0 & 63)) * 8 + (h & 7);
        KT[ad] = (_Float16)acc[t][r];
      }
    } else {                             // V -> VT[b][kt][Gk=keygrp][h][key%8]
      const int h = (g - 8) * 16 + l16;
      f16x4 pk;
      pk[0] = (_Float16)acc[t][0]; pk[1] = (_Float16)acc[t][1];
      pk[2] = (_Float16)acc[t][2]; pk[3] = (_Float16)acc[t][3];
      const size_t ad = ((size_t)((b * 64 + (trbase >> 6)) * 8 + ((trbase & 63) >> 3)) * 512) +
                        (size_t)h * 8 + (trbase & 7);
      *(f16x4*)(VT + ad) = pk;
    }
  }
}

// ---------------------------------------------------------------------------
// Kernel 3: causal flash attention v3 — 32 q-rows per wave (2 row-tiles
// sharing each K/V fragment -> L2 KV traffic HALVED: 528 -> 264 MB; R6
// arithmetic shows v2 ran at ~90% of the 34.5 TB/s L2 ceiling).
// 128 32-row tiles/batch, 4-way kt-split; block = 512 thr = 8 waves =
// tile-pair (jj, 127-jj) x 4 kt-quarters (wave w: tile w>>2, quarter w&3).
// Grid 256 = 1 block/CU, 2 waves/SIMD (same TLP as the R4 winner).
// Barrier-free main loop (wave-private P, stride 68 = conflict-free);
// K loop-carried prefetch, V at step start; one end barrier for the 4-way
// O/l combine in LDS (~105 KB, 1 block/CU). blockIdx%8 -> fixed batch per
// XCD (KV 2MB L2-resident).
// ---------------------------------------------------------------------------
__global__ __launch_bounds__(512) void flash_kernel(
    const _Float16* __restrict__ Qh, const _Float16* __restrict__ KT,
    const _Float16* __restrict__ VT, float* __restrict__ out) {
  __shared__ _Float16 myp[8][32 * 68];   // wave-private P, stride 68 halves
  __shared__ float lds_o[2][4][32][68];  // [tile][quarter][row][h] partials
  __shared__ float lds_l[2][4][32];      // row-sum partials
  const int tid = threadIdx.x;
  const int w = tid >> 6;
  const int lane = tid & 63;
  const int quad = lane >> 4;
  const int l16 = lane & 15;
  const int b = blockIdx.x & 3;
  const int jj = blockIdx.x >> 2;        // 0..63
  const int t = w >> 2;                  // tile slot
  const int q = w & 3;                   // kt quarter
  const int j = t ? (127 - jj) : jj;     // 32-row tile index in batch
  const int qb = j * 32;
  const int nkt = (j >> 1) + 1;          // ceil((qb+31+1)/64)
  const int lo = (nkt * q) >> 2;
  const int hi = (nkt * (q + 1)) >> 2;

  const _Float16* Q = Qh + (size_t)b * SEQ * HEAD;
  const _Float16* KTb = KT + (size_t)b * 64 * 4096;  // 4096 halves per kt
  const _Float16* VTb = VT + (size_t)b * 64 * 4096;
  const f32x4 zero = {0.f, 0.f, 0.f, 0.f};
  _Float16* mp = &myp[w][0];

  // Q A-frags for both 16-row tiles, loaded once
  f16x8 aq0[2], aq1[2];
#pragma unroll
  for (int rt = 0; rt < 2; ++rt) {
    aq0[rt] = *(const f16x8*)(Q + (size_t)(qb + rt * 16 + l16) * HEAD + quad * 8);
    aq1[rt] = *(const f16x8*)(Q + (size_t)(qb + rt * 16 + l16) * HEAD + 32 + quad * 8);
  }

  f32x4 oc[2][4];
#pragma unroll
  for (int rt = 0; rt < 2; ++rt)
#pragma unroll
    for (int m = 0; m < 4; ++m) oc[rt][m] = zero;
  float lacc[2][4] = {{0.f, 0.f, 0.f, 0.f}, {0.f, 0.f, 0.f, 0.f}};

  // K frags for first kt (loop-carried prefetch)
  f16x8 ka[4], kb[4];
  if (lo < hi) {
    const _Float16* kp = KTb + (size_t)lo * 4096;
#pragma unroll
    for (int s = 0; s < 4; ++s) {
      ka[s] = *(const f16x8*)(kp + (size_t)quad * 512 + (s * 16 + l16) * 8);
      kb[s] = *(const f16x8*)(kp + (size_t)(4 + quad) * 512 + (s * 16 + l16) * 8);
    }
  }

  for (int kt = lo; kt < hi; ++kt) {
    // V frag loads (consumed after QK+exp — latency self-hiding)
    const _Float16* vp = VTb + (size_t)kt * 4096;
    f16x8 va[4], vb[4];
#pragma unroll
    for (int m = 0; m < 4; ++m) {
      va[m] = *(const f16x8*)(vp + (size_t)quad * 512 + (m * 16 + l16) * 8);
      vb[m] = *(const f16x8*)(vp + (size_t)(4 + quad) * 512 + (m * 16 + l16) * 8);
    }

    // QK: both row-tiles share the K frags (the 2x reuse that halves L2)
    f32x4 sc[2][4];
#pragma unroll
    for (int s = 0; s < 4; ++s) {
#pragma unroll
      for (int rt = 0; rt < 2; ++rt) {
        sc[rt][s] = __builtin_amdgcn_mfma_f32_16x16x32_f16(aq0[rt], ka[s], zero, 0, 0, 0);
        sc[rt][s] = __builtin_amdgcn_mfma_f32_16x16x32_f16(aq1[rt], kb[s], sc[rt][s], 0, 0, 0);
      }
    }

    // prefetch next step's K (loop-carried, overlaps exp/P/PV)
    if (kt + 1 < hi) {
      const _Float16* kp = KTb + (size_t)(kt + 1) * 4096;
#pragma unroll
      for (int s = 0; s < 4; ++s) {
        ka[s] = *(const f16x8*)(kp + (size_t)quad * 512 + (s * 16 + l16) * 8);
        kb[s] = *(const f16x8*)(kp + (size_t)(4 + quad) * 512 + (s * 16 + l16) * 8);
      }
    }

    // mask (diagonal step only) + exp + wave-private P write
    const int kbase = kt * 64;
    if (kt == nkt - 1) {
#pragma unroll
      for (int rt = 0; rt < 2; ++rt) {
        const int qrow = qb + rt * 16 + quad * 4;
#pragma unroll
        for (int s = 0; s < 4; ++s) {
#pragma unroll
          for (int r = 0; r < 4; ++r) {
            const float pv = (kbase + s * 16 + l16 > qrow + r) ? 0.f : __expf(sc[rt][s][r]);
            lacc[rt][r] += pv;
            mp[(rt * 16 + quad * 4 + r) * 68 + s * 16 + l16] = (_Float16)pv;
          }
        }
      }
    } else {
#pragma unroll
      for (int rt = 0; rt < 2; ++rt) {
#pragma unroll
        for (int s = 0; s < 4; ++s) {
#pragma unroll
          for (int r = 0; r < 4; ++r) {
            const float pv = __expf(sc[rt][s][r]);
            lacc[rt][r] += pv;
            mp[(rt * 16 + quad * 4 + r) * 68 + s * 16 + l16] = (_Float16)pv;
          }
        }
      }
    }

    // PV: both row-tiles share the V frags
#pragma unroll
    for (int rt = 0; rt < 2; ++rt) {
      const f16x8 ap0 = *(const f16x8*)(mp + (rt * 16 + l16) * 68 + quad * 8);
      const f16x8 ap1 = *(const f16x8*)(mp + (rt * 16 + l16) * 68 + 32 + quad * 8);
#pragma unroll
      for (int m = 0; m < 4; ++m) {
        oc[rt][m] = __builtin_amdgcn_mfma_f32_16x16x32_f16(ap0, va[m], oc[rt][m], 0, 0, 0);
        oc[rt][m] = __builtin_amdgcn_mfma_f32_16x16x32_f16(ap1, vb[m], oc[rt][m], 0, 0, 0);
      }
    }
  }

  // deposit quarter partials (empty quarters deposit zeros — still correct)
#pragma unroll
  for (int rt = 0; rt < 2; ++rt) {
#pragma unroll
    for (int r = 0; r < 4; ++r) {
      float l = lacc[rt][r];
      l += __shfl_xor(l, 1);
      l += __shfl_xor(l, 2);
      l += __shfl_xor(l, 4);
      l += __shfl_xor(l, 8);
      const int row = rt * 16 + quad * 4 + r;
      if (l16 == 0) lds_l[t][q][row] = l;
#pragma unroll
      for (int m = 0; m < 4; ++m)
        lds_o[t][q][row][m * 16 + l16] = oc[rt][m][r];
    }
  }
  __syncthreads();

  // combine + normalize + write: wave w covers its tile t, 8 rows per quarter
  {
    const int row = q * 8 + (lane >> 3);          // 0..31 within tile
    const int h8 = (lane & 7) * 8;
    const int jt = t ? (127 - jj) : jj;
    const float lsum = lds_l[t][0][row] + lds_l[t][1][row] +
                       lds_l[t][2][row] + lds_l[t][3][row];
    const float inv = 1.0f / lsum;
    float4 o0, o1;
#pragma unroll
    for (int i = 0; i < 4; ++i) {
      ((float*)&o0)[i] = (lds_o[t][0][row][h8 + i] + lds_o[t][1][row][h8 + i] +
                          lds_o[t][2][row][h8 + i] + lds_o[t][3][row][h8 + i]) * inv;
      ((float*)&o1)[i] = (lds_o[t][0][row][h8 + 4 + i] + lds_o[t][1][row][h8 + 4 + i] +
                          lds_o[t][2][row][h8 + 4 + i] + lds_o[t][3][row][h8 + 4 + i]) * inv;
    }
    float* op = out + ((size_t)b * SEQ + jt * 32 + row) * HEAD + h8;
    *(float4*)op = o0;
    *(float4*)(op + 4) = o1;
  }
}

extern "C" void kernel_launch(void* const* d_in, const int* in_sizes, int n_in,
                              void* d_out, int out_size, void* d_ws, size_t ws_size,
                              hipStream_t stream) {
  const float* x  = (const float*)d_in[0];
  const float* Wk = (const float*)d_in[1];
  const float* Wq = (const float*)d_in[2];
  const float* Wv = (const float*)d_in[3];
  float* out = (float*)d_out;

  // ws layout: Qh[0,2MB) KT[2MB,4MB) VT[4MB,6MB) WT[6MB,6.375MB)
  char* ws = (char*)d_ws;
  _Float16* Qh = (_Float16*)(ws);
  _Float16* KT = (_Float16*)(ws + (size_t)2 * 1024 * 1024);
  _Float16* VT = (_Float16*)(ws + (size_t)4 * 1024 * 1024);
  _Float16* WT = (_Float16*)(ws + (size_t)6 * 1024 * 1024);

  wtrans_kernel<<<96, 256, 0, stream>>>(Wk, Wq, Wv, WT);
  proj_kernel<<<512, 256, 0, stream>>>(x, WT, Qh, KT, VT);
  flash_kernel<<<256, 512, 0, stream>>>(Qh, KT, VT, out);
}

// Round 8
// 132.904 us; speedup vs baseline: 1.0354x; 1.0213x over previous
//
#include <hip/hip_runtime.h>
#include <hip/hip_bf16.h>

typedef _Float16 f16x8 __attribute__((ext_vector_type(8)));
typedef _Float16 f16x4 __attribute__((ext_vector_type(4)));
typedef __fp16 fp16x2 __attribute__((ext_vector_type(2)));
typedef float f32x4 __attribute__((ext_vector_type(4)));

#define BATCH 4
#define SEQ 4096
#define EMB 1024
#define HEAD 64

// Async global->LDS, 16B per lane. LDS dest is WAVE-UNIFORM base; HW adds
// lane*16. Global src is per-lane (we make it base + lane*16 = coalesced,
// or pre-swizzled for conflict-free LDS reads — m173 pattern).
__device__ __forceinline__ void async_copy16(const void* gsrc, void* ldst) {
  __builtin_amdgcn_global_load_lds(
      (const __attribute__((address_space(1))) void*)gsrc,
      (__attribute__((address_space(3))) void*)ldst,
      16, 0, 0);
}

// ---------------------------------------------------------------------------
// Kernel 1: weights -> glds-tiled WT (unchanged).
// ---------------------------------------------------------------------------
__global__ __launch_bounds__(256) void wtrans_kernel(
    const float* __restrict__ Wk, const float* __restrict__ Wq,
    const float* __restrict__ Wv, _Float16* __restrict__ WT) {
  int id = blockIdx.x * 256 + threadIdx.x;   // 0 .. 24575 (unit index)
  int step = id / 1536;
  int rem = id - step * 1536;
  int G = rem / 192;
  int n = rem - G * 192;
  int sel = n >> 6;
  int col = n & 63;
  const float* src = (sel == 0) ? Wq : (sel == 1) ? Wk : Wv;
  const float scale = (sel == 0) ? 0.03125f : 1.0f;
  f16x8 u;
#pragma unroll
  for (int j = 0; j < 8; ++j) {
    int k = step * 64 + G * 8 + j;
    u[j] = (_Float16)(src[k * 64 + col] * scale);
  }
  *(f16x8*)(WT + (size_t)id * 8) = u;
}

// ---------------------------------------------------------------------------
// Kernel 2: QKV projection — counted-vmcnt pipeline + K-STEP ROTATION.
// R4 counters: proj's HBM portion ran at 968 GB/s (15% of achievable) and
// was exactly the critical path. Cause theory: every block reads the SAME
// 64-col window x[:, s*64..] each step — 256B segments at uniform 4KB
// stride -> HBM channel camping (channel-select bits constant device-wide).
// Fix: block processes K-steps in rotated order ks = (step + blk%16) & 15
// (acc order-invariant), decorrelating column windows -> all channels
// active. WT staging rotates identically (384KB, L2-resident either way).
// Everything else identical to R7.
// ---------------------------------------------------------------------------
__global__ __launch_bounds__(256) void proj_kernel(
    const float* __restrict__ x, const _Float16* __restrict__ WT,
    _Float16* __restrict__ Qh, _Float16* __restrict__ KT,
    _Float16* __restrict__ VT) {
  __shared__ _Float16 wtl[2][12288];   // 2 x 24 KB, unit u = G*192 + n
  __shared__ float xls[3][32 * 64];    // 3 x 8 KB x tile ring, swizzled units
  const int tid = threadIdx.x;
  const int wave = tid >> 6;
  const int lane = tid & 63;
  const int quad = lane >> 4;
  const int l16 = lane & 15;
  const int wm = wave & 1;
  const int wn = wave >> 1;
  const int rowblk = blockIdx.x * 32;
  const int koff = blockIdx.x & 15;    // K-step rotation offset

  const int lq = lane >> 4;
  const int pos = lane & 15;

  f32x4 acc[6];
#pragma unroll
  for (int t = 0; t < 6; ++t) acc[t] = (f32x4){0.f, 0.f, 0.f, 0.f};

  // prologue: WT(ks0) -> wtl[0]; x(ks0) -> xls[0]; x(ks1) -> xls[1]
  {
    const int ks0 = koff;
    const int ks1 = (koff + 1) & 15;
    const _Float16* wsrc = WT + (size_t)ks0 * 12288;
#pragma unroll
    for (int i = 0; i < 6; ++i) {
      const int c = wave * 6 + i;
      async_copy16(wsrc + (size_t)c * 512 + lane * 8, (char*)&wtl[0][0] + c * 1024);
    }
#pragma unroll
    for (int i = 0; i < 2; ++i) {
      const int c = wave * 2 + i;
      const int rts = c * 4 + lq;
      const int u = pos ^ (rts & 7);
      async_copy16(x + (size_t)(rowblk + rts) * EMB + ks0 * 64 + u * 4,
                   (char*)&xls[0][0] + c * 1024);
    }
#pragma unroll
    for (int i = 0; i < 2; ++i) {
      const int c = wave * 2 + i;
      const int rts = c * 4 + lq;
      const int u = pos ^ (rts & 7);
      async_copy16(x + (size_t)(rowblk + rts) * EMB + ks1 * 64 + u * 4,
                   (char*)&xls[1][0] + c * 1024);
    }
  }

  const int rt = wm * 16 + l16;
  const int rb = rt & 7;
  const int ua = ((quad * 2) ^ rb) * 4;
  const int ub = ((quad * 2 + 1) ^ rb) * 4;
  const int uc = ((8 + quad * 2) ^ rb) * 4;
  const int ud = ((8 + quad * 2 + 1) ^ rb) * 4;

  int pw = 0;
  int x3 = 0;
  int x3i = 2;
  for (int step = 0; step < 16; ++step) {
    if (step < 15) {
      asm volatile("s_waitcnt vmcnt(2)" ::: "memory");
    } else {
      asm volatile("s_waitcnt vmcnt(0)" ::: "memory");
    }
    __builtin_amdgcn_sched_barrier(0);
    __builtin_amdgcn_s_barrier();

    if (step + 1 < 16) {
      const int ksn = (step + 1 + koff) & 15;
      const _Float16* wsrc = WT + (size_t)ksn * 12288;
#pragma unroll
      for (int i = 0; i < 6; ++i) {
        const int c = wave * 6 + i;
        async_copy16(wsrc + (size_t)c * 512 + lane * 8,
                     (char*)&wtl[pw ^ 1][0] + c * 1024);
      }
    }
    if (step + 2 < 16) {
      const int ksn = (step + 2 + koff) & 15;
      const float* xsrc = x + (size_t)ksn * 64;
#pragma unroll
      for (int i = 0; i < 2; ++i) {
        const int c = wave * 2 + i;
        const int rts = c * 4 + lq;
        const int u = pos ^ (rts & 7);
        async_copy16(xsrc + (size_t)(rowblk + rts) * EMB + u * 4,
                     (char*)&xls[x3i][0] + c * 1024);
      }
    }

    const float* xl = &xls[x3][rt * 64];
    const float4 xa = *(const float4*)(xl + ua);
    const float4 xb = *(const float4*)(xl + ub);
    const float4 xc = *(const float4*)(xl + uc);
    const float4 xd = *(const float4*)(xl + ud);
    fp16x2 p0 = __builtin_amdgcn_cvt_pkrtz(xa.x, xa.y);
    fp16x2 p1 = __builtin_amdgcn_cvt_pkrtz(xa.z, xa.w);
    fp16x2 p2 = __builtin_amdgcn_cvt_pkrtz(xb.x, xb.y);
    fp16x2 p3 = __builtin_amdgcn_cvt_pkrtz(xb.z, xb.w);
    f16x8 af0, af1;
    af0[0] = (_Float16)p0[0]; af0[1] = (_Float16)p0[1];
    af0[2] = (_Float16)p1[0]; af0[3] = (_Float16)p1[1];
    af0[4] = (_Float16)p2[0]; af0[5] = (_Float16)p2[1];
    af0[6] = (_Float16)p3[0]; af0[7] = (_Float16)p3[1];
    p0 = __builtin_amdgcn_cvt_pkrtz(xc.x, xc.y);
    p1 = __builtin_amdgcn_cvt_pkrtz(xc.z, xc.w);
    p2 = __builtin_amdgcn_cvt_pkrtz(xd.x, xd.y);
    p3 = __builtin_amdgcn_cvt_pkrtz(xd.z, xd.w);
    af1[0] = (_Float16)p0[0]; af1[1] = (_Float16)p0[1];
    af1[2] = (_Float16)p1[0]; af1[3] = (_Float16)p1[1];
    af1[4] = (_Float16)p2[0]; af1[5] = (_Float16)p2[1];
    af1[6] = (_Float16)p3[0]; af1[7] = (_Float16)p3[1];
#pragma unroll
    for (int t = 0; t < 6; ++t) {
      const int n = wn * 96 + t * 16 + l16;
      const f16x8 b0 = *(const f16x8*)&wtl[pw][(size_t)((0 * 4 + quad) * 192 + n) * 8];
      const f16x8 b1 = *(const f16x8*)&wtl[pw][(size_t)((1 * 4 + quad) * 192 + n) * 8];
      acc[t] = __builtin_amdgcn_mfma_f32_16x16x32_f16(af0, b0, acc[t], 0, 0, 0);
      acc[t] = __builtin_amdgcn_mfma_f32_16x16x32_f16(af1, b1, acc[t], 0, 0, 0);
    }
    pw ^= 1;
    x3 = (x3 == 2) ? 0 : x3 + 1;
    x3i = (x3i == 2) ? 0 : x3i + 1;
  }

  const int rowbase = rowblk + wm * 16;
  const int b = rowbase >> 12;
  const int trbase = (rowbase & 4095) + quad * 4;
#pragma unroll
  for (int t = 0; t < 6; ++t) {
    const int g = wn * 6 + t;
    if (g < 4) {                         // Q row-major (scaled via Wq)
      const int h = g * 16 + l16;
#pragma unroll
      for (int r = 0; r < 4; ++r)
        Qh[(size_t)(rowbase + quad * 4 + r) * HEAD + h] = (_Float16)acc[t][r];
    } else if (g < 8) {                  // K -> KT[b][kt][G=h/8][key][h%8]
      const int h = (g - 4) * 16 + l16;
#pragma unroll
      for (int r = 0; r < 4; ++r) {
        const int t0 = trbase + r;
        const size_t ad = ((size_t)((b * 64 + (t0 >> 6)) * 8 + (h >> 3)) * 64 +
                           (t0 & 63)) * 8 + (h & 7);
        KT[ad] = (_Float16)acc[t][r];
      }
    } else {                             // V -> VT[b][kt][Gk=keygrp][h][key%8]
      const int h = (g - 8) * 16 + l16;
      f16x4 pk;
      pk[0] = (_Float16)acc[t][0]; pk[1] = (_Float16)acc[t][1];
      pk[2] = (_Float16)acc[t][2]; pk[3] = (_Float16)acc[t][3];
      const size_t ad = ((size_t)((b * 64 + (trbase >> 6)) * 8 + ((trbase & 63) >> 3)) * 512) +
                        (size_t)h * 8 + (trbase & 7);
      *(f16x4*)(VT + ad) = pk;
    }
  }
}

// ---------------------------------------------------------------------------
// Kernel 3: causal flash attention v3 — 32 q-rows per wave (unchanged from
// R7: ~15 us, within 1.8x of its 8.6 us MFMA floor).
// ---------------------------------------------------------------------------
__global__ __launch_bounds__(512) void flash_kernel(
    const _Float16* __restrict__ Qh, const _Float16* __restrict__ KT,
    const _Float16* __restrict__ VT, float* __restrict__ out) {
  __shared__ _Float16 myp[8][32 * 68];   // wave-private P, stride 68 halves
  __shared__ float lds_o[2][4][32][68];  // [tile][quarter][row][h] partials
  __shared__ float lds_l[2][4][32];      // row-sum partials
  const int tid = threadIdx.x;
  const int w = tid >> 6;
  const int lane = tid & 63;
  const int quad = lane >> 4;
  const int l16 = lane & 15;
  const int b = blockIdx.x & 3;
  const int jj = blockIdx.x >> 2;        // 0..63
  const int t = w >> 2;                  // tile slot
  const int q = w & 3;                   // kt quarter
  const int j = t ? (127 - jj) : jj;     // 32-row tile index in batch
  const int qb = j * 32;
  const int nkt = (j >> 1) + 1;          // ceil((qb+31+1)/64)
  const int lo = (nkt * q) >> 2;
  const int hi = (nkt * (q + 1)) >> 2;

  const _Float16* Q = Qh + (size_t)b * SEQ * HEAD;
  const _Float16* KTb = KT + (size_t)b * 64 * 4096;  // 4096 halves per kt
  const _Float16* VTb = VT + (size_t)b * 64 * 4096;
  const f32x4 zero = {0.f, 0.f, 0.f, 0.f};
  _Float16* mp = &myp[w][0];

  // Q A-frags for both 16-row tiles, loaded once
  f16x8 aq0[2], aq1[2];
#pragma unroll
  for (int rt = 0; rt < 2; ++rt) {
    aq0[rt] = *(const f16x8*)(Q + (size_t)(qb + rt * 16 + l16) * HEAD + quad * 8);
    aq1[rt] = *(const f16x8*)(Q + (size_t)(qb + rt * 16 + l16) * HEAD + 32 + quad * 8);
  }

  f32x4 oc[2][4];
#pragma unroll
  for (int rt = 0; rt < 2; ++rt)
#pragma unroll
    for (int m = 0; m < 4; ++m) oc[rt][m] = zero;
  float lacc[2][4] = {{0.f, 0.f, 0.f, 0.f}, {0.f, 0.f, 0.f, 0.f}};

  // K frags for first kt (loop-carried prefetch)
  f16x8 ka[4], kb[4];
  if (lo < hi) {
    const _Float16* kp = KTb + (size_t)lo * 4096;
#pragma unroll
    for (int s = 0; s < 4; ++s) {
      ka[s] = *(const f16x8*)(kp + (size_t)quad * 512 + (s * 16 + l16) * 8);
      kb[s] = *(const f16x8*)(kp + (size_t)(4 + quad) * 512 + (s * 16 + l16) * 8);
    }
  }

  for (int kt = lo; kt < hi; ++kt) {
    // V frag loads (consumed after QK+exp — latency self-hiding)
    const _Float16* vp = VTb + (size_t)kt * 4096;
    f16x8 va[4], vb[4];
#pragma unroll
    for (int m = 0; m < 4; ++m) {
      va[m] = *(const f16x8*)(vp + (size_t)quad * 512 + (m * 16 + l16) * 8);
      vb[m] = *(const f16x8*)(vp + (size_t)(4 + quad) * 512 + (m * 16 + l16) * 8);
    }

    // QK: both row-tiles share the K frags (the 2x reuse that halves L2)
    f32x4 sc[2][4];
#pragma unroll
    for (int s = 0; s < 4; ++s) {
#pragma unroll
      for (int rt = 0; rt < 2; ++rt) {
        sc[rt][s] = __builtin_amdgcn_mfma_f32_16x16x32_f16(aq0[rt], ka[s], zero, 0, 0, 0);
        sc[rt][s] = __builtin_amdgcn_mfma_f32_16x16x32_f16(aq1[rt], kb[s], sc[rt][s], 0, 0, 0);
      }
    }

    // prefetch next step's K (loop-carried, overlaps exp/P/PV)
    if (kt + 1 < hi) {
      const _Float16* kp = KTb + (size_t)(kt + 1) * 4096;
#pragma unroll
      for (int s = 0; s < 4; ++s) {
        ka[s] = *(const f16x8*)(kp + (size_t)quad * 512 + (s * 16 + l16) * 8);
        kb[s] = *(const f16x8*)(kp + (size_t)(4 + quad) * 512 + (s * 16 + l16) * 8);
      }
    }

    // mask (diagonal step only) + exp + wave-private P write
    const int kbase = kt * 64;
    if (kt == nkt - 1) {
#pragma unroll
      for (int rt = 0; rt < 2; ++rt) {
        const int qrow = qb + rt * 16 + quad * 4;
#pragma unroll
        for (int s = 0; s < 4; ++s) {
#pragma unroll
          for (int r = 0; r < 4; ++r) {
            const float pv = (kbase + s * 16 + l16 > qrow + r) ? 0.f : __expf(sc[rt][s][r]);
            lacc[rt][r] += pv;
            mp[(rt * 16 + quad * 4 + r) * 68 + s * 16 + l16] = (_Float16)pv;
          }
        }
      }
    } else {
#pragma unroll
      for (int rt = 0; rt < 2; ++rt) {
#pragma unroll
        for (int s = 0; s < 4; ++s) {
#pragma unroll
          for (int r = 0; r < 4; ++r) {
            const float pv = __expf(sc[rt][s][r]);
            lacc[rt][r] += pv;
            mp[(rt * 16 + quad * 4 + r) * 68 + s * 16 + l16] = (_Float16)pv;
          }
        }
      }
    }

    // PV: both row-tiles share the V frags
#pragma unroll
    for (int rt = 0; rt < 2; ++rt) {
      const f16x8 ap0 = *(const f16x8*)(mp + (rt * 16 + l16) * 68 + quad * 8);
      const f16x8 ap1 = *(const f16x8*)(mp + (rt * 16 + l16) * 68 + 32 + quad * 8);
#pragma unroll
      for (int m = 0; m < 4; ++m) {
        oc[rt][m] = __builtin_amdgcn_mfma_f32_16x16x32_f16(ap0, va[m], oc[rt][m], 0, 0, 0);
        oc[rt][m] = __builtin_amdgcn_mfma_f32_16x16x32_f16(ap1, vb[m], oc[rt][m], 0, 0, 0);
      }
    }
  }

  // deposit quarter partials (empty quarters deposit zeros — still correct)
#pragma unroll
  for (int rt = 0; rt < 2; ++rt) {
#pragma unroll
    for (int r = 0; r < 4; ++r) {
      float l = lacc[rt][r];
      l += __shfl_xor(l, 1);
      l += __shfl_xor(l, 2);
      l += __shfl_xor(l, 4);
      l += __shfl_xor(l, 8);
      const int row = rt * 16 + quad * 4 + r;
      if (l16 == 0) lds_l[t][q][row] = l;
#pragma unroll
      for (int m = 0; m < 4; ++m)
        lds_o[t][q][row][m * 16 + l16] = oc[rt][m][r];
    }
  }
  __syncthreads();

  // combine + normalize + write: wave w covers its tile t, 8 rows per quarter
  {
    const int row = q * 8 + (lane >> 3);          // 0..31 within tile
    const int h8 = (lane & 7) * 8;
    const int jt = t ? (127 - jj) : jj;
    const float lsum = lds_l[t][0][row] + lds_l[t][1][row] +
                       lds_l[t][2][row] + lds_l[t][3][row];
    const float inv = 1.0f / lsum;
    float4 o0, o1;
#pragma unroll
    for (int i = 0; i < 4; ++i) {
      ((float*)&o0)[i] = (lds_o[t][0][row][h8 + i] + lds_o[t][1][row][h8 + i] +
                          lds_o[t][2][row][h8 + i] + lds_o[t][3][row][h8 + i]) * inv;
      ((float*)&o1)[i] = (lds_o[t][0][row][h8 + 4 + i] + lds_o[t][1][row][h8 + 4 + i] +
                          lds_o[t][2][row][h8 + 4 + i] + lds_o[t][3][row][h8 + 4 + i]) * inv;
    }
    float* op = out + ((size_t)b * SEQ + jt * 32 + row) * HEAD + h8;
    *(float4*)op = o0;
    *(float4*)(op + 4) = o1;
  }
}

extern "C" void kernel_launch(void* const* d_in, const int* in_sizes, int n_in,
                              void* d_out, int out_size, void* d_ws, size_t ws_size,
                              hipStream_t stream) {
  const float* x  = (const float*)d_in[0];
  const float* Wk = (const float*)d_in[1];
  const float* Wq = (const float*)d_in[2];
  const float* Wv = (const float*)d_in[3];
  float* out = (float*)d_out;

  // ws layout: Qh[0,2MB) KT[2MB,4MB) VT[4MB,6MB) WT[6MB,6.375MB)
  char* ws = (char*)d_ws;
  _Float16* Qh = (_Float16*)(ws);
  _Float16* KT = (_Float16*)(ws + (size_t)2 * 1024 * 1024);
  _Float16* VT = (_Float16*)(ws + (size_t)4 * 1024 * 1024);
  _Float16* WT = (_Float16*)(ws + (size_t)6 * 1024 * 1024);

  wtrans_kernel<<<96, 256, 0, stream>>>(Wk, Wq, Wv, WT);
  proj_kernel<<<512, 256, 0, stream>>>(x, WT, Qh, KT, VT);
  flash_kernel<<<256, 512, 0, stream>>>(Qh, KT, VT, out);
}